// Round 6
// baseline (508.704 us; speedup 1.0000x reference)
//
#include <hip/hip_runtime.h>
#include <hip/hip_bf16.h>

#define D_MODEL 768
#define NSEQ    8192
#define NBATCH  4
#define MROWS   (NBATCH*NSEQ)   // 32768
#define CHUNK   64
#define NCHUNK  (NSEQ/CHUNK)    // 128

// GEMM1 tile: BM=128, BN=192, BK=64, 4 waves 2x2, wave tile 64x96
#define BM 128
#define BN 192
#define BK 64

typedef __attribute__((ext_vector_type(8)))  short bshort8;
typedef __attribute__((ext_vector_type(16))) float f32x16;

__device__ __forceinline__ float bf2f(ushort u){
  union { unsigned int i; float f; } x; x.i = ((unsigned int)u) << 16; return x.f;
}
__device__ __forceinline__ ushort f2bf(float f){
  union { float f; unsigned int i; } x; x.f = f;
  unsigned int r = x.i + 0x7fffu + ((x.i >> 16) & 1u);
  return (ushort)(r >> 16);
}
__device__ __forceinline__ float silu_f(float v){ return v / (1.0f + __expf(-v)); }

__device__ __forceinline__ void async_copy16(const ushort* g, ushort* l){
  __builtin_amdgcn_global_load_lds((const __attribute__((address_space(1))) void*)g,
                                   (__attribute__((address_space(3))) void*)l, 16, 0, 0);
}

// ---------------- weight transpose + bf16 convert: in[R][C] f32 -> out[C][R] bf16
__global__ void tr_cvt(const float* __restrict__ in, ushort* __restrict__ out, int R, int C){
  __shared__ float tile[32][33];
  int c0 = blockIdx.x*32, r0 = blockIdx.y*32;
  int tx = threadIdx.x & 31, ty = threadIdx.x >> 5;
  #pragma unroll
  for (int p=0;p<4;p++){
    int r = ty + p*8;
    tile[r][tx] = in[(size_t)(r0+r)*C + c0 + tx];
  }
  __syncthreads();
  #pragma unroll
  for (int p=0;p<4;p++){
    int c = ty + p*8;
    out[(size_t)(c0+c)*R + r0 + tx] = f2bf(tile[tx][c]);
  }
}

// ---------------- GEMM1: A fp32 [M][768] converted in-kernel, BT bf16 [N][K].
// 128x192 tile, BK=64, 32x32x16 MFMA, swizzled LDS (round-3 proven compute loop).
// LDS: physical 16B slot p holds logical (row r=p>>3, chunk (p&7)^(r&7)).
// N=1536, block cols uniform: bn<4 -> xc bf16; bn>=4 -> silu -> z bf16
__global__ __launch_bounds__(256) void gemm1_bt(
    const float* __restrict__ Af, const ushort* __restrict__ BT,
    ushort* __restrict__ oxc, ushort* __restrict__ oz)
{
  const int K = 768;
  __shared__ __align__(16) ushort Asm[BM*BK];   // 16 KB
  __shared__ __align__(16) ushort Bsm[BN*BK];   // 24 KB
  const int tid = threadIdx.x;
  const int bm = blockIdx.x, bn = blockIdx.y;
  const int lane = tid & 63, wid = tid >> 6;
  const int wm = (wid >> 1) * 64, wn = (wid & 1) * 96;
  const int l31 = lane & 31, half = lane >> 5;

  // A staging: 4 x (8 fp32 -> 8 bf16 = 16B) per thread, swizzled dest
  const float* Ag[4]; int Ap[4];
  #pragma unroll
  for (int it=0; it<4; ++it){
    int p  = it*256 + tid;
    int r  = p >> 3;
    int cl = (p & 7) ^ (r & 7);
    Ag[it] = Af + (size_t)(bm*BM + r)*K + cl*8;
    Ap[it] = p*8;
  }
  // B staging: 6 x 16B DMA per thread
  const ushort* Bg[6]; ushort* Bl[6];
  #pragma unroll
  for (int it=0; it<6; ++it){
    int p  = it*256 + tid;
    int r  = p >> 3;
    int cl = (p & 7) ^ (r & 7);
    Bg[it] = BT + (size_t)(bn*BN + r)*K + cl*8;
    Bl[it] = Bsm + p*8;
  }

  int arow[2], ar7[2], brow[3], br7[3];
  #pragma unroll
  for (int i=0;i<2;i++){
    int ra = wm + i*32 + l31; arow[i] = ra*BK; ar7[i] = ra & 7;
  }
  #pragma unroll
  for (int j=0;j<3;j++){
    int rb = wn + j*32 + l31; brow[j] = rb*BK; br7[j] = rb & 7;
  }

  f32x16 acc[2][3];
  #pragma unroll
  for (int i=0;i<2;i++)
    #pragma unroll
    for (int j=0;j<3;j++)
      #pragma unroll
      for (int r=0;r<16;r++) acc[i][j][r] = 0.f;

  const int KT = K / BK;  // 12
  for (int kt=0; kt<KT; ++kt){
    __syncthreads();
    #pragma unroll
    for (int it=0; it<6; ++it){ async_copy16(Bg[it], Bl[it]); Bg[it] += BK; }
    float4 f0[4], f1[4];
    #pragma unroll
    for (int it=0; it<4; ++it){
      f0[it] = *(const float4*)(Ag[it]);
      f1[it] = *(const float4*)(Ag[it] + 4);
      Ag[it] += BK;
    }
    #pragma unroll
    for (int it=0; it<4; ++it){
      __hip_bfloat162 h[4];
      h[0] = __float22bfloat162_rn(make_float2(f0[it].x, f0[it].y));
      h[1] = __float22bfloat162_rn(make_float2(f0[it].z, f0[it].w));
      h[2] = __float22bfloat162_rn(make_float2(f1[it].x, f1[it].y));
      h[3] = __float22bfloat162_rn(make_float2(f1[it].z, f1[it].w));
      *(ulonglong2*)(Asm + Ap[it]) = *(const ulonglong2*)h;
    }
    asm volatile("s_waitcnt vmcnt(0)" ::: "memory");
    __syncthreads();

    #pragma unroll
    for (int s=0; s<4; ++s){
      const int c = s*2 + half;
      bshort8 av[2], bv[3];
      #pragma unroll
      for (int i=0;i<2;i++)
        av[i] = *(const bshort8*)(Asm + arow[i] + ((c ^ ar7[i]) << 3));
      #pragma unroll
      for (int j=0;j<3;j++)
        bv[j] = *(const bshort8*)(Bsm + brow[j] + ((c ^ br7[j]) << 3));
      #pragma unroll
      for (int i=0;i<2;i++)
        #pragma unroll
        for (int j=0;j<3;j++)
          acc[i][j] = __builtin_amdgcn_mfma_f32_32x32x16_bf16(av[i], bv[j], acc[i][j], 0,0,0);
    }
  }

  // epilogue: C/D 32x32: col=lane&31, row=(reg&3)+8*(reg>>2)+4*(lane>>5)
  if (bn < 4){
    #pragma unroll
    for (int i=0;i<2;i++){
      const int Rbase = bm*BM + wm + i*32 + 4*half;
      #pragma unroll
      for (int j=0;j<3;j++){
        const int Cc = bn*BN + wn + j*32 + l31;
        #pragma unroll
        for (int reg=0; reg<16; reg++){
          const int R = Rbase + (reg & 3) + 8*(reg >> 2);
          oxc[(size_t)R*768 + Cc] = f2bf(acc[i][j][reg]);
        }
      }
    }
  } else {
    #pragma unroll
    for (int i=0;i<2;i++){
      const int Rbase = bm*BM + wm + i*32 + 4*half;
      #pragma unroll
      for (int j=0;j<3;j++){
        const int Cc = bn*BN - 768 + wn + j*32 + l31;
        #pragma unroll
        for (int reg=0; reg<16; reg++){
          const int R = Rbase + (reg & 3) + 8*(reg >> 2);
          oz[(size_t)R*768 + Cc] = f2bf(silu_f(acc[i][j][reg]));
        }
      }
    }
  }
}

// ---------------- GEMM2: BM=64, BN=192, BK=64, fp32 out. Grid 512x4 = 2048 light blocks.
#define BM2 64
__global__ __launch_bounds__(256) void gemm2_bt(
    const ushort* __restrict__ A, const ushort* __restrict__ BT,
    float* __restrict__ of, int K)
{
  __shared__ __align__(16) ushort Asm[BM2*BK];  // 8 KB
  __shared__ __align__(16) ushort Bsm[BN*BK];   // 24 KB
  const int tid = threadIdx.x;
  const int bm = blockIdx.x, bn = blockIdx.y;
  const int lane = tid & 63, wid = tid >> 6;
  const int wm = (wid >> 1) * 32, wn = (wid & 1) * 96;
  const int l31 = lane & 31, half = lane >> 5;

  const ushort* Ag[2]; ushort* Al[2];
  #pragma unroll
  for (int it=0; it<2; ++it){
    int p  = it*256 + tid;
    int r  = p >> 3;
    int cl = (p & 7) ^ (r & 7);
    Ag[it] = A + (size_t)(bm*BM2 + r)*K + cl*8;
    Al[it] = Asm + p*8;
  }
  const ushort* Bg[6]; ushort* Bl[6];
  #pragma unroll
  for (int it=0; it<6; ++it){
    int p  = it*256 + tid;
    int r  = p >> 3;
    int cl = (p & 7) ^ (r & 7);
    Bg[it] = BT + (size_t)(bn*BN + r)*K + cl*8;
    Bl[it] = Bsm + p*8;
  }

  int arow, ar7, brow[3], br7[3];
  { int ra = wm + l31; arow = ra*BK; ar7 = ra & 7; }
  #pragma unroll
  for (int j=0;j<3;j++){
    int rb = wn + j*32 + l31; brow[j] = rb*BK; br7[j] = rb & 7;
  }

  f32x16 acc[3];
  #pragma unroll
  for (int j=0;j<3;j++)
    #pragma unroll
    for (int r=0;r<16;r++) acc[j][r] = 0.f;

  const int KT = K / BK;  // 12
  for (int kt=0; kt<KT; ++kt){
    __syncthreads();
    #pragma unroll
    for (int it=0; it<2; ++it){ async_copy16(Ag[it], Al[it]); Ag[it] += BK; }
    #pragma unroll
    for (int it=0; it<6; ++it){ async_copy16(Bg[it], Bl[it]); Bg[it] += BK; }
    asm volatile("s_waitcnt vmcnt(0)" ::: "memory");
    __syncthreads();

    #pragma unroll
    for (int s=0; s<4; ++s){
      const int c = s*2 + half;
      bshort8 av, bv[3];
      av = *(const bshort8*)(Asm + arow + ((c ^ ar7) << 3));
      #pragma unroll
      for (int j=0;j<3;j++)
        bv[j] = *(const bshort8*)(Bsm + brow[j] + ((c ^ br7[j]) << 3));
      #pragma unroll
      for (int j=0;j<3;j++)
        acc[j] = __builtin_amdgcn_mfma_f32_32x32x16_bf16(av, bv[j], acc[j], 0,0,0);
    }
  }

  const int Rbase = bm*BM2 + wm + 4*half;
  #pragma unroll
  for (int j=0;j<3;j++){
    const int Cc = bn*BN + wn + j*32 + l31;
    #pragma unroll
    for (int reg=0; reg<16; reg++){
      const int R = Rbase + (reg & 3) + 8*(reg >> 2);
      of[(size_t)R*768 + Cc] = acc[j][reg];
    }
  }
}

// ---------------- pass 1: conv+silu, per-chunk sums; 2 channels/thread, ushort2 loads
__global__ void conv_psum(const ushort* __restrict__ xc, const float* __restrict__ cw,
                          const float* __restrict__ cb, float* __restrict__ psum){
  int c0 = threadIdx.x * 2;               // 0..766
  int b = blockIdx.z, ch = blockIdx.x;
  int t0 = ch*CHUNK;
  const ushort* xp = xc + (size_t)b*NSEQ*768 + c0;
  float w0a=cw[c0*3+0], w1a=cw[c0*3+1], w2a=cw[c0*3+2], ba=cb[c0];
  float w0b=cw[c0*3+3], w1b=cw[c0*3+4], w2b=cw[c0*3+5], bb=cb[c0+1];
  float am2=0.f, am1=0.f, bm2=0.f, bm1=0.f;
  if (t0>=2){ ushort2 u = *(const ushort2*)(xp + (size_t)(t0-2)*768); am2=bf2f(u.x); bm2=bf2f(u.y); }
  if (t0>=1){ ushort2 u = *(const ushort2*)(xp + (size_t)(t0-1)*768); am1=bf2f(u.x); bm1=bf2f(u.y); }
  float sa=0.f, sb=0.f;
  #pragma unroll 4
  for (int i=0;i<CHUNK;i++){
    ushort2 u = *(const ushort2*)(xp + (size_t)(t0+i)*768);
    float xa = bf2f(u.x), xb = bf2f(u.y);
    sa += silu_f(w0a*am2 + w1a*am1 + w2a*xa + ba);
    sb += silu_f(w0b*bm2 + w1b*bm1 + w2b*xb + bb);
    am2=am1; am1=xa; bm2=bm1; bm1=xb;
  }
  float2* pp = (float2*)(psum + ((size_t)b*NCHUNK + ch)*768 + c0);
  *pp = make_float2(sa, sb);
}

// ---------------- pass 2: wave-parallel exclusive scan over NCHUNK=128 per (b,c)
__global__ void scan_chunks(const float* __restrict__ psum, float* __restrict__ offs){
  int wv   = (blockIdx.x*256 + threadIdx.x) >> 6;  // 0..3071
  int lane = threadIdx.x & 63;
  int b = wv / 768, c = wv % 768;
  size_t base = ((size_t)b*NCHUNK)*768 + c;
  int ch0 = lane*2;
  float v0 = psum[base + (size_t)ch0*768];
  float v1 = psum[base + (size_t)(ch0+1)*768];
  float pair = v0 + v1;
  float inc = pair;
  #pragma unroll
  for (int d=1; d<64; d<<=1){
    float t = __shfl_up(inc, d, 64);
    if (lane >= d) inc += t;
  }
  float excl = inc - pair;
  offs[base + (size_t)ch0*768]     = excl;
  offs[base + (size_t)(ch0+1)*768] = excl + v0;
}

// ---------------- pass 3: replay conv+silu, apply SSM + gate -> v bf16 (v aliases z!)
__global__ void scan_apply(const ushort* __restrict__ xc, const ushort* zb,
                           const float* __restrict__ cw, const float* __restrict__ cb,
                           const float* __restrict__ Bm, const float* __restrict__ Cm,
                           const float* __restrict__ Dv, const float* __restrict__ offs,
                           ushort* v){
  int c0 = threadIdx.x * 2;
  int b = blockIdx.z, ch = blockIdx.x;
  int t0 = ch*CHUNK;
  size_t base = (size_t)b*NSEQ*768 + c0;
  const ushort* xp = xc + base;
  const ushort* zp = zb + base;
  ushort* vp = v + base;
  float w0a=cw[c0*3+0], w1a=cw[c0*3+1], w2a=cw[c0*3+2], ba=cb[c0];
  float w0b=cw[c0*3+3], w1b=cw[c0*3+4], w2b=cw[c0*3+5], bb=cb[c0+1];
  float bca=0.f, bcb=0.f;
  #pragma unroll
  for (int s=0;s<8;s++){ bca += Bm[c0*8+s]*Cm[c0*8+s]; bcb += Bm[c0*8+8+s]*Cm[c0*8+8+s]; }
  float dda = Dv[c0], ddb = Dv[c0+1];
  const float2 off2 = *(const float2*)(offs + ((size_t)b*NCHUNK + ch)*768 + c0);
  float cua = off2.x, cub = off2.y;
  float am2=0.f, am1=0.f, bm2=0.f, bm1=0.f;
  if (t0>=2){ ushort2 u = *(const ushort2*)(xp + (size_t)(t0-2)*768); am2=bf2f(u.x); bm2=bf2f(u.y); }
  if (t0>=1){ ushort2 u = *(const ushort2*)(xp + (size_t)(t0-1)*768); am1=bf2f(u.x); bm1=bf2f(u.y); }
  #pragma unroll 4
  for (int i=0;i<CHUNK;i++){
    size_t o = (size_t)(t0+i)*768;
    ushort2 u = *(const ushort2*)(xp + o);
    ushort2 z2 = *(const ushort2*)(zp + o);
    float xa = bf2f(u.x), xb = bf2f(u.y);
    float ua = silu_f(w0a*am2 + w1a*am1 + w2a*xa + ba);
    float ub = silu_f(w0b*bm2 + w1b*bm1 + w2b*xb + bb);
    cua += ua; cub += ub;
    float ya = bca*cua + dda*ua;
    float yb = bcb*cub + ddb*ub;
    ushort2 o2; o2.x = f2bf(ya * bf2f(z2.x)); o2.y = f2bf(yb * bf2f(z2.y));
    *(ushort2*)(vp + o) = o2;
    am2=am1; am1=xa; bm2=bm1; bm1=xb;
  }
}

extern "C" void kernel_launch(void* const* d_in, const int* in_sizes, int n_in,
                              void* d_out, int out_size, void* d_ws, size_t ws_size,
                              hipStream_t stream)
{
  const float* x      = (const float*)d_in[0];
  const float* W_in   = (const float*)d_in[1];
  const float* conv_w = (const float*)d_in[2];
  const float* conv_b = (const float*)d_in[3];
  const float* Bm     = (const float*)d_in[4];
  const float* Cm     = (const float*)d_in[5];
  const float* Dv     = (const float*)d_in[6];
  const float* W_out  = (const float*)d_in[7];
  float* out = (float*)d_out;

  char* ws = (char*)d_ws;
  ushort* xcbf  = (ushort*)(ws + 0);          // 50331648
  ushort* zbf   = (ushort*)(ws + 50331648);   // 50331648 ; becomes v in-place
  ushort* wint  = (ushort*)(ws + 100663296);  // 2359296
  ushort* woutt = (ushort*)(ws + 103022592);  // 1179648
  float*  psum  = (float*)(ws + 104202240);   // 1572864
  float*  offs  = (float*)(ws + 105775104);   // 1572864
  if (ws_size < 107347968) return;

  tr_cvt<<<dim3(1536/32, 768/32), 256, 0, stream>>>(W_in,  wint,  768, 1536);
  tr_cvt<<<dim3(768/32,  768/32), 256, 0, stream>>>(W_out, woutt, 768, 768);

  gemm1_bt<<<dim3(MROWS/BM, 1536/BN), 256, 0, stream>>>(x, wint, xcbf, zbf);

  conv_psum  <<<dim3(NCHUNK, 1, NBATCH), 384, 0, stream>>>(xcbf, conv_w, conv_b, psum);
  scan_chunks<<<768, 256, 0, stream>>>(psum, offs);
  scan_apply <<<dim3(NCHUNK, 1, NBATCH), 384, 0, stream>>>(xcbf, zbf, conv_w, conv_b,
                                                           Bm, Cm, Dv, offs, zbf /*v in-place*/);

  gemm2_bt<<<dim3(MROWS/BM2, 768/BN), 256, 0, stream>>>(zbf, woutt, out, 768);
}